// Round 5
// baseline (178.210 us; speedup 1.0000x reference)
//
#include <hip/hip_runtime.h>
#include <hip/hip_bf16.h>

// out[m,o] = sum_k x[m,k] * (W[o,k]*scale) + bias[o]
// M=1024, K=4096, N=11008.
// Pre-pass: W(int32)->bf16 + X(f32)->bf16 into d_ws.
// GEMM: 256x256 tile, BK=64, 512 thr (8 waves 2Mx4N, per-wave 128x64).
// Deep pipeline: LDS = 4-slot K-half ring per operand (slot = tile-parity*2 + kh,
// 16KB/slot). stage(t+1,kh1) at tile start, stage(t+2,kh0) mid-tile; gate
// vmcnt(12) => each K-half has ~6 phases of latency cover; never drains.
// 64B-row slots with sigma-granule swizzle: LDS granule l of a 16-row group
// holds (row l&15, K-granule (l>>4)^(l&3)); read granule = lr | ((kb^(lr&3))<<4).

#define M_TOT 1024
#define N_TOT 11008
#define K_TOT 4096
#define BM 256
#define BN 256
#define BK 64
#define NT (K_TOT / BK)   // 64 K-tiles
#define ASLOT_B 16384     // one K-half slot: 256 rows x 32 bf16 = 16 KB
#define BBASE   65536     // B region starts at 64 KB

typedef __attribute__((ext_vector_type(8))) short short8;   // 8 bf16
typedef __attribute__((ext_vector_type(4))) float f32x4;

__device__ __forceinline__ unsigned short f2bf(float f) {
    __hip_bfloat16 h = __float2bfloat16(f);  // RNE
    return __builtin_bit_cast(unsigned short, h);
}

__device__ __forceinline__ void gload16(const void* g, void* l) {
    __builtin_amdgcn_global_load_lds(
        (const __attribute__((address_space(1))) unsigned int*)g,
        (__attribute__((address_space(3))) unsigned int*)l,
        16, 0, 0);
}

// ---------------- pre-pass: W int32->bf16 (exact) and X f32->bf16 ----------------
__global__ void conv_kernel(const int* __restrict__ W, const float* __restrict__ X,
                            __hip_bfloat16* __restrict__ Wb, __hip_bfloat16* __restrict__ Xb,
                            int wn8, int xn8) {
    int idx = blockIdx.x * blockDim.x + threadIdx.x;
    int stride = gridDim.x * blockDim.x;
    int total = wn8 + xn8;
    for (int i = idx; i < total; i += stride) {
        short8 o;
        if (i < wn8) {
            const int4* p = (const int4*)W + (size_t)i * 2;
            int4 a = p[0], b = p[1];
            o[0] = (short)f2bf((float)a.x); o[1] = (short)f2bf((float)a.y);
            o[2] = (short)f2bf((float)a.z); o[3] = (short)f2bf((float)a.w);
            o[4] = (short)f2bf((float)b.x); o[5] = (short)f2bf((float)b.y);
            o[6] = (short)f2bf((float)b.z); o[7] = (short)f2bf((float)b.w);
            *(short8*)(Wb + (size_t)i * 8) = o;
        } else {
            int j = i - wn8;
            const f32x4* p = (const f32x4*)X + (size_t)j * 2;
            f32x4 a = p[0], b = p[1];
            o[0] = (short)f2bf(a[0]); o[1] = (short)f2bf(a[1]);
            o[2] = (short)f2bf(a[2]); o[3] = (short)f2bf(a[3]);
            o[4] = (short)f2bf(b[0]); o[5] = (short)f2bf(b[1]);
            o[6] = (short)f2bf(b[2]); o[7] = (short)f2bf(b[3]);
            *(short8*)(Xb + (size_t)j * 8) = o;
        }
    }
}

// ---------------- main GEMM ----------------
__global__ __launch_bounds__(512, 2)
void gemm_bf16_kernel(const __hip_bfloat16* __restrict__ Xb,   // [1024,4096]
                      const __hip_bfloat16* __restrict__ Wb,   // [11008,4096]
                      const float* __restrict__ scale,
                      const float* __restrict__ bias,
                      float* __restrict__ out) {               // [1024,11008]
    __shared__ __align__(16) unsigned char lds[131072];   // A: [0,64K) 4 slots; B: [64K,128K)

    const int tid  = threadIdx.x;     // 0..511
    const int lane = tid & 63;
    const int wid  = tid >> 6;        // 0..7
    const int wr   = wid >> 2;        // 0..1  (128-row strip)
    const int wc   = wid & 3;         // 0..3  (64-col strip)
    const int lr   = lane & 15;
    const int kb   = lane >> 4;       // 0..3

    const int brow = blockIdx.y * BM;
    const int bcol = blockIdx.x * BN;

    // ---- staging addressing (per wave: 32 rows A + 32 rows B per K-half = 2+2 gloads) ----
    // LDS dest linear (wave-uniform base + lane*16); global source carries the
    // sigma swizzle: lane l sources (row l&15 of its 16-row group,
    // K-granule (l>>4)^(l&3)) so LDS granule l holds exactly that.
    const int s_rowoff = wid * 32 + lr;                 // lane&15 == lr
    const int s_cswz   = ((kb ^ (lane & 3)) * 8);       // bf16 elems within 32-elem K-half

    const __hip_bfloat16* asrc = Xb + (size_t)(brow + s_rowoff) * K_TOT + s_cswz;
    const __hip_bfloat16* bsrc = Wb + (size_t)(bcol + s_rowoff) * K_TOT + s_cswz;
    unsigned char* adst = lds + wid * 2048;             // + slot*16384 + g*1024
    unsigned char* bdst = lds + BBASE + wid * 2048;

    auto stage = [&](int tau, int kh) {
        const int slot = ((tau & 1) << 1) | kh;
        const size_t koff = (size_t)((tau & (NT - 1)) * 64 + kh * 32);
#pragma unroll
        for (int g = 0; g < 2; ++g) {
            gload16(asrc + koff + (size_t)g * 16 * K_TOT, adst + slot * ASLOT_B + g * 1024);
            gload16(bsrc + koff + (size_t)g * 16 * K_TOT, bdst + slot * ASLOT_B + g * 1024);
        }
    };

    // ---- read addressing ----
    // byte within a 1KB 16-row group: granule = lr | ((kb ^ (lr&3)) << 4), *16
    const int rg16 = ((lr | ((kb ^ (lr & 3)) << 4)) << 4);

    f32x4 acc[8][4];
#pragma unroll
    for (int m = 0; m < 8; ++m)
#pragma unroll
        for (int n = 0; n < 4; ++n)
#pragma unroll
            for (int i = 0; i < 4; ++i) acc[m][n][i] = 0.0f;

    // prologue: slots 0,1,2 <- (t0,kh0),(t0,kh1),(t1,kh0)   [12 gloads/wave]
    stage(0, 0);
    stage(0, 1);
    stage(1, 0);

    for (int t = 0; t < NT; ++t) {
        const int slot0 = ((t & 1) << 1);       // tile t, kh0
        const int slot1 = slot0 | 1;            // tile t, kh1

        // ================= K-half 0 =================
        stage(t + 1, 1);                                   // -> slot of (t+1,kh1), freed end of t-1
        asm volatile("s_waitcnt vmcnt(12)" ::: "memory");  // (t,kh0) landed; 3 half-groups in flight
        __builtin_amdgcn_s_barrier();
        {
            const unsigned char* sa = lds + slot0 * ASLOT_B;
            const unsigned char* sb = lds + BBASE + slot0 * ASLOT_B;
            short8 af[4], af2[4], bfr[4];
#pragma unroll
            for (int m = 0; m < 4; ++m)
                af[m] = *(const short8*)(sa + (wr * 8 + m) * 1024 + rg16);
#pragma unroll
            for (int n = 0; n < 4; ++n)
                bfr[n] = *(const short8*)(sb + (wc * 4 + n) * 1024 + rg16);
#pragma unroll
            for (int m = 0; m < 4; ++m)
                af2[m] = *(const short8*)(sa + (wr * 8 + 4 + m) * 1024 + rg16);
            __builtin_amdgcn_s_setprio(1);
#pragma unroll
            for (int m = 0; m < 4; ++m)
#pragma unroll
                for (int n = 0; n < 4; ++n)
                    acc[m][n] = __builtin_amdgcn_mfma_f32_16x16x32_bf16(af[m], bfr[n], acc[m][n], 0, 0, 0);
#pragma unroll
            for (int m = 0; m < 4; ++m)
#pragma unroll
                for (int n = 0; n < 4; ++n)
                    acc[4 + m][n] = __builtin_amdgcn_mfma_f32_16x16x32_bf16(af2[m], bfr[n], acc[4 + m][n], 0, 0, 0);
            __builtin_amdgcn_s_setprio(0);
        }
        __builtin_amdgcn_s_barrier();                      // kh0-slot reads done (WAR for next stage)

        // ================= K-half 1 =================
        stage(t + 2, 0);                                   // overwrites slot0 (freed above)
        asm volatile("s_waitcnt vmcnt(12)" ::: "memory");  // (t,kh1) landed
        __builtin_amdgcn_s_barrier();
        {
            const unsigned char* sa = lds + slot1 * ASLOT_B;
            const unsigned char* sb = lds + BBASE + slot1 * ASLOT_B;
            short8 af[4], af2[4], bfr[4];
#pragma unroll
            for (int m = 0; m < 4; ++m)
                af[m] = *(const short8*)(sa + (wr * 8 + m) * 1024 + rg16);
#pragma unroll
            for (int n = 0; n < 4; ++n)
                bfr[n] = *(const short8*)(sb + (wc * 4 + n) * 1024 + rg16);
#pragma unroll
            for (int m = 0; m < 4; ++m)
                af2[m] = *(const short8*)(sa + (wr * 8 + 4 + m) * 1024 + rg16);
            __builtin_amdgcn_s_setprio(1);
#pragma unroll
            for (int m = 0; m < 4; ++m)
#pragma unroll
                for (int n = 0; n < 4; ++n)
                    acc[m][n] = __builtin_amdgcn_mfma_f32_16x16x32_bf16(af[m], bfr[n], acc[m][n], 0, 0, 0);
#pragma unroll
            for (int m = 0; m < 4; ++m)
#pragma unroll
                for (int n = 0; n < 4; ++n)
                    acc[4 + m][n] = __builtin_amdgcn_mfma_f32_16x16x32_bf16(af2[m], bfr[n], acc[4 + m][n], 0, 0, 0);
            __builtin_amdgcn_s_setprio(0);
        }
        __builtin_amdgcn_s_barrier();                      // kh1-slot reads done (WAR for next P0 stage)
    }

    // epilogue: out = acc * scale + bias
    const float sc = scale[0];
    const int orow0 = brow + wr * 128;
    const int ocol0 = bcol + wc * 64;
    float bv[4];
#pragma unroll
    for (int n = 0; n < 4; ++n) bv[n] = bias[ocol0 + n * 16 + lr];
#pragma unroll
    for (int m = 0; m < 8; ++m) {
#pragma unroll
        for (int i = 0; i < 4; ++i) {
            int r = orow0 + m * 16 + kb * 4 + i;   // C/D: row=(lane>>4)*4+reg, col=lane&15
            size_t base = (size_t)r * N_TOT + ocol0;
#pragma unroll
            for (int n = 0; n < 4; ++n)
                out[base + n * 16 + lr] = acc[m][n][i] * sc + bv[n];
        }
    }
}

// ---------------- fallback (round-1 fused kernel) if ws too small ----------------
__device__ __forceinline__ unsigned long long pack4(float a, float b, float c, float d) {
    return (unsigned long long)f2bf(a)
         | ((unsigned long long)f2bf(b) << 16)
         | ((unsigned long long)f2bf(c) << 32)
         | ((unsigned long long)f2bf(d) << 48);
}

#define FBM 128
#define FBN 128

__global__ __launch_bounds__(256, 2)
void otf_linear_fused(const float* __restrict__ X, const int* __restrict__ W,
                      const float* __restrict__ scale, const float* __restrict__ bias,
                      float* __restrict__ out) {
    __shared__ __align__(16) unsigned char AsB[FBM * BK * 2];
    __shared__ __align__(16) unsigned char BsB[FBN * BK * 2];

    const int tid = threadIdx.x, lane = tid & 63, wid = tid >> 6;
    const int wr = wid >> 1, wc = wid & 1, lr = lane & 15, kb = lane >> 4;
    const int brow = blockIdx.y * FBM, bcol = blockIdx.x * FBN;
    const int srow = tid >> 4, sc4 = tid & 15;

    f32x4 areg[8];
    int4 breg[8];
    auto load_tiles = [&](int t) {
        const int k0 = t * BK;
#pragma unroll
        for (int p = 0; p < 8; ++p) {
            int row = p * 16 + srow;
            areg[p] = *(const f32x4*)(&X[(size_t)(brow + row) * K_TOT + k0 + sc4 * 4]);
            breg[p] = *(const int4*)(&W[(size_t)(bcol + row) * K_TOT + k0 + sc4 * 4]);
        }
    };
    auto store_tiles = [&]() {
#pragma unroll
        for (int p = 0; p < 8; ++p) {
            int row = p * 16 + srow;
            int boff = (sc4 * 8) ^ ((row & 7) << 4);
            *(unsigned long long*)(&AsB[row * 128 + boff]) =
                pack4(areg[p][0], areg[p][1], areg[p][2], areg[p][3]);
            *(unsigned long long*)(&BsB[row * 128 + boff]) =
                pack4((float)breg[p].x, (float)breg[p].y, (float)breg[p].z, (float)breg[p].w);
        }
    };

    f32x4 acc[4][4];
#pragma unroll
    for (int m = 0; m < 4; ++m)
#pragma unroll
        for (int n = 0; n < 4; ++n)
#pragma unroll
            for (int i = 0; i < 4; ++i) acc[m][n][i] = 0.0f;

    load_tiles(0);
    for (int t = 0; t < NT; ++t) {
        store_tiles();
        __syncthreads();
        if (t + 1 < NT) load_tiles(t + 1);
#pragma unroll
        for (int kk = 0; kk < 2; ++kk) {
            short8 af[4], bfr[4];
#pragma unroll
            for (int m = 0; m < 4; ++m) {
                int row = wr * 64 + m * 16 + lr;
                int col = (kk * 64 + kb * 16) ^ ((row & 7) << 4);
                af[m] = *(const short8*)(&AsB[row * 128 + col]);
            }
#pragma unroll
            for (int n = 0; n < 4; ++n) {
                int row = wc * 64 + n * 16 + lr;
                int col = (kk * 64 + kb * 16) ^ ((row & 7) << 4);
                bfr[n] = *(const short8*)(&BsB[row * 128 + col]);
            }
#pragma unroll
            for (int m = 0; m < 4; ++m)
#pragma unroll
                for (int n = 0; n < 4; ++n)
                    acc[m][n] = __builtin_amdgcn_mfma_f32_16x16x32_bf16(af[m], bfr[n], acc[m][n], 0, 0, 0);
        }
        __syncthreads();
    }

    const float sc = scale[0];
    const int orow0 = brow + wr * 64, ocol0 = bcol + wc * 64;
    float bv[4];
#pragma unroll
    for (int n = 0; n < 4; ++n) bv[n] = bias[ocol0 + n * 16 + lr];
#pragma unroll
    for (int m = 0; m < 4; ++m)
#pragma unroll
        for (int i = 0; i < 4; ++i) {
            int r = orow0 + m * 16 + kb * 4 + i;
            size_t base = (size_t)r * N_TOT + ocol0;
#pragma unroll
            for (int n = 0; n < 4; ++n)
                out[base + n * 16 + lr] = acc[m][n][i] * sc + bv[n];
        }
}

extern "C" void kernel_launch(void* const* d_in, const int* in_sizes, int n_in,
                              void* d_out, int out_size, void* d_ws, size_t ws_size,
                              hipStream_t stream) {
    const float* x     = (const float*)d_in[0];
    const int*   w     = (const int*)d_in[1];
    const float* scale = (const float*)d_in[2];
    const float* bias  = (const float*)d_in[3];
    float* out = (float*)d_out;

    const size_t W_ELEMS = (size_t)N_TOT * K_TOT;   // 45,088,768
    const size_t X_ELEMS = (size_t)M_TOT * K_TOT;   //  4,194,304
    const size_t need = (W_ELEMS + X_ELEMS) * sizeof(__hip_bfloat16);  // ~94 MB

    if (ws_size >= need) {
        __hip_bfloat16* Wb = (__hip_bfloat16*)d_ws;
        __hip_bfloat16* Xb = (__hip_bfloat16*)((char*)d_ws + W_ELEMS * 2);
        conv_kernel<<<2048, 256, 0, stream>>>(w, x, Wb, Xb,
                                              (int)(W_ELEMS / 8), (int)(X_ELEMS / 8));
        gemm_bf16_kernel<<<dim3(N_TOT / BN, M_TOT / BM), 512, 0, stream>>>(Xb, Wb, scale, bias, out);
    } else {
        otf_linear_fused<<<dim3(N_TOT / FBN, M_TOT / FBM), 256, 0, stream>>>(x, w, scale, bias, out);
    }
}

// Round 7
// 145.919 us; speedup vs baseline: 1.2213x; 1.2213x over previous
//
#include <hip/hip_runtime.h>
#include <hip/hip_bf16.h>

// out[m,o] = sum_k x[m,k] * (W[o,k]*scale) + bias[o]
// M=1024, K=4096, N=11008.
// Pre-pass: W(int32)->bf16 + X(f32)->bf16 into d_ws.
// GEMM: 256x256 tile, BK=64, 512 thr (8 waves 2Mx4N, per-wave 128x64),
// dbuf 2x64KB LDS, R4 row-XOR swizzle (pre-swizzled global source, linear
// gload_lds dest, swizzled ds_read). Schedule: 2 barriers/tile only.
//   stageA(t+1) -> vmcnt(4) -> BARRIER(visibility) -> reads+MFMA quadrants
//   interleaved (compiler emits counted lgkmcnt from reg deps; later read
//   groups stay in flight under earlier MFMA clusters) -> stageB(t+1) mid-
//   tile -> lgkmcnt(0) -> BARRIER(WAR).
// R6's NaN root cause fixed: every ds_read of tile-t data now follows the
// barrier that published ALL waves' tile-t global_load_lds writes.

#define M_TOT 1024
#define N_TOT 11008
#define K_TOT 4096
#define BM 256
#define BN 256
#define BK 64
#define NT (K_TOT / BK)  // 64 K-tiles (even)
#define ABYTES (BM * BK * 2)          // 32 KB
#define BUFB   ((BM + BN) * BK * 2)   // 64 KB per buffer

typedef __attribute__((ext_vector_type(8))) short short8;   // 8 bf16
typedef __attribute__((ext_vector_type(4))) float f32x4;

__device__ __forceinline__ unsigned short f2bf(float f) {
    __hip_bfloat16 h = __float2bfloat16(f);  // RNE
    return __builtin_bit_cast(unsigned short, h);
}

__device__ __forceinline__ void gload16(const void* g, void* l) {
    __builtin_amdgcn_global_load_lds(
        (const __attribute__((address_space(1))) unsigned int*)g,
        (__attribute__((address_space(3))) unsigned int*)l,
        16, 0, 0);
}

// ---------------- pre-pass: W int32->bf16 (exact) and X f32->bf16 ----------------
__global__ void conv_kernel(const int* __restrict__ W, const float* __restrict__ X,
                            __hip_bfloat16* __restrict__ Wb, __hip_bfloat16* __restrict__ Xb,
                            int wn8, int xn8) {
    int idx = blockIdx.x * blockDim.x + threadIdx.x;
    int stride = gridDim.x * blockDim.x;
    int total = wn8 + xn8;
    for (int i = idx; i < total; i += stride) {
        short8 o;
        if (i < wn8) {
            const int4* p = (const int4*)W + (size_t)i * 2;
            int4 a = p[0], b = p[1];
            o[0] = (short)f2bf((float)a.x); o[1] = (short)f2bf((float)a.y);
            o[2] = (short)f2bf((float)a.z); o[3] = (short)f2bf((float)a.w);
            o[4] = (short)f2bf((float)b.x); o[5] = (short)f2bf((float)b.y);
            o[6] = (short)f2bf((float)b.z); o[7] = (short)f2bf((float)b.w);
            *(short8*)(Wb + (size_t)i * 8) = o;
        } else {
            int j = i - wn8;
            const f32x4* p = (const f32x4*)X + (size_t)j * 2;
            f32x4 a = p[0], b = p[1];
            o[0] = (short)f2bf(a[0]); o[1] = (short)f2bf(a[1]);
            o[2] = (short)f2bf(a[2]); o[3] = (short)f2bf(a[3]);
            o[4] = (short)f2bf(b[0]); o[5] = (short)f2bf(b[1]);
            o[6] = (short)f2bf(b[2]); o[7] = (short)f2bf(b[3]);
            *(short8*)(Xb + (size_t)j * 8) = o;
        }
    }
}

// ---------------- main GEMM ----------------
__global__ __launch_bounds__(512, 2)
void gemm_bf16_kernel(const __hip_bfloat16* __restrict__ Xb,   // [1024,4096]
                      const __hip_bfloat16* __restrict__ Wb,   // [11008,4096]
                      const float* __restrict__ scale,
                      const float* __restrict__ bias,
                      float* __restrict__ out) {               // [1024,11008]
    __shared__ __align__(16) unsigned char lds[2 * BUFB];      // 128 KB

    const int tid  = threadIdx.x;     // 0..511
    const int lane = tid & 63;
    const int wid  = tid >> 6;        // 0..7
    const int wr   = wid >> 2;        // 0..1  (128-row half)
    const int wc   = wid & 3;         // 0..3  (64-col strip)
    const int lr   = lane & 15;
    const int kb   = lane >> 4;       // 0..3

    const int brow = blockIdx.y * BM;
    const int bcol = blockIdx.x * BN;

    // staging: per wave 32 rows A + 32 rows B, 4 chunks of 8 rows each.
    // gload_lds dest linear; global source col pre-swizzled so LDS content
    // matches the read-side XOR: src col = ((l&7) ^ (l>>3)) * 8 elems.
    const int s_row  = wid * 32 + (lane >> 3);
    const int s_cole = (((lane & 7) ^ (lane >> 3)) * 8);

    const __hip_bfloat16* asrc0 = Xb + (size_t)(brow + s_row) * K_TOT + s_cole;
    const __hip_bfloat16* bsrc0 = Wb + (size_t)(bcol + s_row) * K_TOT + s_cole;
    const int lds_row0 = wid * 32;

    auto stageA = [&](int t, unsigned char* buf) {
        const size_t k0 = (size_t)t * BK;
#pragma unroll
        for (int i = 0; i < 4; ++i)
            gload16(asrc0 + k0 + (size_t)i * 8 * K_TOT, buf + (lds_row0 + i * 8) * 128);
    };
    auto stageB = [&](int t, unsigned char* buf) {
        const size_t k0 = (size_t)t * BK;
#pragma unroll
        for (int i = 0; i < 4; ++i)
            gload16(bsrc0 + k0 + (size_t)i * 8 * K_TOT, buf + ABYTES + (lds_row0 + i * 8) * 128);
    };

    f32x4 acc[8][4];
#pragma unroll
    for (int m = 0; m < 8; ++m)
#pragma unroll
        for (int n = 0; n < 4; ++n)
#pragma unroll
            for (int i = 0; i < 4; ++i) acc[m][n][i] = 0.0f;

    // one K-tile: reads cur (visible after the barrier), stages tile tn -> nxt
    auto do_tile = [&](const unsigned char* cur, unsigned char* nxt, int tn) {
        stageA(tn, nxt);
        asm volatile("s_waitcnt vmcnt(4)" ::: "memory");   // tile-t A,B landed (this wave)
        __builtin_amdgcn_s_barrier();                      // ...and all waves' => cur visible
        __builtin_amdgcn_sched_barrier(0);                 // pin reads below the barrier

        short8 a0[4], a1[4], a2[4], a3[4], b0[4], b1[4];
        const int c0 = (kb * 8) * 2;          // kk=0 byte col
        const int c1 = (32 + kb * 8) * 2;     // kk=1 byte col

        // G0: B(kk0) + A(kk0, m-half0)
#pragma unroll
        for (int n = 0; n < 4; ++n) {
            int row = wc * 64 + n * 16 + lr;
            b0[n] = *(const short8*)(cur + ABYTES + row * 128 + (c0 ^ ((row & 7) << 4)));
        }
#pragma unroll
        for (int m = 0; m < 4; ++m) {
            int row = wr * 128 + m * 16 + lr;
            a0[m] = *(const short8*)(cur + row * 128 + (c0 ^ ((row & 7) << 4)));
        }
        // G1: A(kk0, m-half1)
#pragma unroll
        for (int m = 0; m < 4; ++m) {
            int row = wr * 128 + 64 + m * 16 + lr;
            a1[m] = *(const short8*)(cur + row * 128 + (c0 ^ ((row & 7) << 4)));
        }

        // P0 (compiler waits counted lgkm for G0 only; G1 stays in flight)
        __builtin_amdgcn_s_setprio(1);
#pragma unroll
        for (int m = 0; m < 4; ++m)
#pragma unroll
            for (int n = 0; n < 4; ++n)
                acc[m][n] = __builtin_amdgcn_mfma_f32_16x16x32_bf16(a0[m], b0[n], acc[m][n], 0, 0, 0);
        __builtin_amdgcn_s_setprio(0);

        // G2: B(kk1) + A(kk1, m-half0)  — issues under P0/P1 execution
#pragma unroll
        for (int n = 0; n < 4; ++n) {
            int row = wc * 64 + n * 16 + lr;
            b1[n] = *(const short8*)(cur + ABYTES + row * 128 + (c1 ^ ((row & 7) << 4)));
        }
#pragma unroll
        for (int m = 0; m < 4; ++m) {
            int row = wr * 128 + m * 16 + lr;
            a2[m] = *(const short8*)(cur + row * 128 + (c1 ^ ((row & 7) << 4)));
        }

        // P1
        __builtin_amdgcn_s_setprio(1);
#pragma unroll
        for (int m = 0; m < 4; ++m)
#pragma unroll
            for (int n = 0; n < 4; ++n)
                acc[4 + m][n] = __builtin_amdgcn_mfma_f32_16x16x32_bf16(a1[m], b0[n], acc[4 + m][n], 0, 0, 0);
        __builtin_amdgcn_s_setprio(0);

        // G3: A(kk1, m-half1); stage B of next tile mid-compute
#pragma unroll
        for (int m = 0; m < 4; ++m) {
            int row = wr * 128 + 64 + m * 16 + lr;
            a3[m] = *(const short8*)(cur + row * 128 + (c1 ^ ((row & 7) << 4)));
        }
        stageB(tn, nxt);

        // P2
        __builtin_amdgcn_s_setprio(1);
#pragma unroll
        for (int m = 0; m < 4; ++m)
#pragma unroll
            for (int n = 0; n < 4; ++n)
                acc[m][n] = __builtin_amdgcn_mfma_f32_16x16x32_bf16(a2[m], b1[n], acc[m][n], 0, 0, 0);
        __builtin_amdgcn_s_setprio(0);

        // P3
        __builtin_amdgcn_s_setprio(1);
#pragma unroll
        for (int m = 0; m < 4; ++m)
#pragma unroll
            for (int n = 0; n < 4; ++n)
                acc[4 + m][n] = __builtin_amdgcn_mfma_f32_16x16x32_bf16(a3[m], b1[n], acc[4 + m][n], 0, 0, 0);
        __builtin_amdgcn_s_setprio(0);

        asm volatile("s_waitcnt lgkmcnt(0)" ::: "memory"); // all reads of cur retired
        __builtin_amdgcn_s_barrier();                      // WAR: cur may be re-staged next tile
    };

    unsigned char* buf0 = lds;
    unsigned char* buf1 = lds + BUFB;

    // prologue: tile 0 -> buf0 (8 loads in flight)
    stageA(0, buf0);
    stageB(0, buf0);

    // 2 K-tiles per iteration: compile-time buffer roles
    for (int t = 0; t < NT; t += 2) {
        do_tile(buf0, buf1, t + 1);                        // tile t   reads buf0, stages t+1
        do_tile(buf1, buf0, (t + 2 < NT) ? t + 2 : 0);     // tile t+1 reads buf1, stages t+2 (wrap harmless)
    }

    // epilogue: out = acc * scale + bias
    const float sc = scale[0];
    const int orow0 = brow + wr * 128;
    const int ocol0 = bcol + wc * 64;
    float bv[4];
#pragma unroll
    for (int n = 0; n < 4; ++n) bv[n] = bias[ocol0 + n * 16 + lr];
#pragma unroll
    for (int m = 0; m < 8; ++m) {
#pragma unroll
        for (int i = 0; i < 4; ++i) {
            int r = orow0 + m * 16 + kb * 4 + i;   // C/D: row=(lane>>4)*4+reg, col=lane&15
            size_t base = (size_t)r * N_TOT + ocol0;
#pragma unroll
            for (int n = 0; n < 4; ++n)
                out[base + n * 16 + lr] = acc[m][n][i] * sc + bv[n];
        }
    }
}

// ---------------- fallback (round-1 fused kernel) if ws too small ----------------
__device__ __forceinline__ unsigned long long pack4(float a, float b, float c, float d) {
    return (unsigned long long)f2bf(a)
         | ((unsigned long long)f2bf(b) << 16)
         | ((unsigned long long)f2bf(c) << 32)
         | ((unsigned long long)f2bf(d) << 48);
}

#define FBM 128
#define FBN 128

__global__ __launch_bounds__(256, 2)
void otf_linear_fused(const float* __restrict__ X, const int* __restrict__ W,
                      const float* __restrict__ scale, const float* __restrict__ bias,
                      float* __restrict__ out) {
    __shared__ __align__(16) unsigned char AsB[FBM * BK * 2];
    __shared__ __align__(16) unsigned char BsB[FBN * BK * 2];

    const int tid = threadIdx.x, lane = tid & 63, wid = tid >> 6;
    const int wr = wid >> 1, wc = wid & 1, lr = lane & 15, kb = lane >> 4;
    const int brow = blockIdx.y * FBM, bcol = blockIdx.x * FBN;
    const int srow = tid >> 4, sc4 = tid & 15;

    f32x4 areg[8];
    int4 breg[8];
    auto load_tiles = [&](int t) {
        const int k0 = t * BK;
#pragma unroll
        for (int p = 0; p < 8; ++p) {
            int row = p * 16 + srow;
            areg[p] = *(const f32x4*)(&X[(size_t)(brow + row) * K_TOT + k0 + sc4 * 4]);
            breg[p] = *(const int4*)(&W[(size_t)(bcol + row) * K_TOT + k0 + sc4 * 4]);
        }
    };
    auto store_tiles = [&]() {
#pragma unroll
        for (int p = 0; p < 8; ++p) {
            int row = p * 16 + srow;
            int boff = (sc4 * 8) ^ ((row & 7) << 4);
            *(unsigned long long*)(&AsB[row * 128 + boff]) =
                pack4(areg[p][0], areg[p][1], areg[p][2], areg[p][3]);
            *(unsigned long long*)(&BsB[row * 128 + boff]) =
                pack4((float)breg[p].x, (float)breg[p].y, (float)breg[p].z, (float)breg[p].w);
        }
    };

    f32x4 acc[4][4];
#pragma unroll
    for (int m = 0; m < 4; ++m)
#pragma unroll
        for (int n = 0; n < 4; ++n)
#pragma unroll
            for (int i = 0; i < 4; ++i) acc[m][n][i] = 0.0f;

    load_tiles(0);
    for (int t = 0; t < NT; ++t) {
        store_tiles();
        __syncthreads();
        if (t + 1 < NT) load_tiles(t + 1);
#pragma unroll
        for (int kk = 0; kk < 2; ++kk) {
            short8 af[4], bfr[4];
#pragma unroll
            for (int m = 0; m < 4; ++m) {
                int row = wr * 64 + m * 16 + lr;
                int col = (kk * 64 + kb * 16) ^ ((row & 7) << 4);
                af[m] = *(const short8*)(&AsB[row * 128 + col]);
            }
#pragma unroll
            for (int n = 0; n < 4; ++n) {
                int row = wc * 64 + n * 16 + lr;
                int col = (kk * 64 + kb * 16) ^ ((row & 7) << 4);
                bfr[n] = *(const short8*)(&BsB[row * 128 + col]);
            }
#pragma unroll
            for (int m = 0; m < 4; ++m)
#pragma unroll
                for (int n = 0; n < 4; ++n)
                    acc[m][n] = __builtin_amdgcn_mfma_f32_16x16x32_bf16(af[m], bfr[n], acc[m][n], 0, 0, 0);
        }
        __syncthreads();
    }

    const float sc = scale[0];
    const int orow0 = brow + wr * 64, ocol0 = bcol + wc * 64;
    float bv[4];
#pragma unroll
    for (int n = 0; n < 4; ++n) bv[n] = bias[ocol0 + n * 16 + lr];
#pragma unroll
    for (int m = 0; m < 4; ++m)
#pragma unroll
        for (int i = 0; i < 4; ++i) {
            int r = orow0 + m * 16 + kb * 4 + i;
            size_t base = (size_t)r * N_TOT + ocol0;
#pragma unroll
            for (int n = 0; n < 4; ++n)
                out[base + n * 16 + lr] = acc[m][n][i] * sc + bv[n];
        }
}

extern "C" void kernel_launch(void* const* d_in, const int* in_sizes, int n_in,
                              void* d_out, int out_size, void* d_ws, size_t ws_size,
                              hipStream_t stream) {
    const float* x     = (const float*)d_in[0];
    const int*   w     = (const int*)d_in[1];
    const float* scale = (const float*)d_in[2];
    const float* bias  = (const float*)d_in[3];
    float* out = (float*)d_out;

    const size_t W_ELEMS = (size_t)N_TOT * K_TOT;   // 45,088,768
    const size_t X_ELEMS = (size_t)M_TOT * K_TOT;   //  4,194,304
    const size_t need = (W_ELEMS + X_ELEMS) * sizeof(__hip_bfloat16);  // ~94 MB

    if (ws_size >= need) {
        __hip_bfloat16* Wb = (__hip_bfloat16*)d_ws;
        __hip_bfloat16* Xb = (__hip_bfloat16*)((char*)d_ws + W_ELEMS * 2);
        conv_kernel<<<2048, 256, 0, stream>>>(w, x, Wb, Xb,
                                              (int)(W_ELEMS / 8), (int)(X_ELEMS / 8));
        gemm_bf16_kernel<<<dim3(N_TOT / BN, M_TOT / BM), 512, 0, stream>>>(Xb, Wb, scale, bias, out);
    } else {
        otf_linear_fused<<<dim3(N_TOT / FBN, M_TOT / FBM), 256, 0, stream>>>(x, w, scale, bias, out);
    }
}

// Round 8
// 96.477 us; speedup vs baseline: 1.8472x; 1.5125x over previous
//
#include <hip/hip_runtime.h>
#include <hip/hip_bf16.h>

// out[m,o] = sum_k x[m,k] * (W[o,k]*scale) + bias[o]
// M=1024, K=4096, N=11008.
// INT8 path: W int32 -> i8 pack (exact). X f32 -> per-row i8 quant (row scale
// sx[m] = rowmax/127). GEMM mfma_i32_16x16x64_i8 (2x bf16 rate, i32-exact
// accum). Epilogue: out = acc * (sx[row]*scale) + bias.
// GEMM structure = R7 (verified): 256x256 tile, BK=128 i8 (128-B rows), 512
// thr (8 waves 2Mx4N), dbuf 2x64KB LDS, row-XOR swizzle (pre-swizzled global
// source + linear gload_lds dest + swizzled ds_read), 2 barriers/tile:
//   stageA(t+1) -> vmcnt(4) -> BARRIER -> read/MFMA groups interleaved,
//   stageB(t+1) mid-tile -> lgkmcnt(0) -> BARRIER.

#define M_TOT 1024
#define N_TOT 11008
#define K_TOT 4096
#define BM 256
#define BN 256
#define BKI 128                       // K-tile in i8 elems (= 128-B rows)
#define NTI (K_TOT / BKI)             // 32 K-tiles (even)
#define ABYTES (BM * BKI)             // 32 KB
#define BUFB   ((BM + BN) * BKI)      // 64 KB per buffer

typedef __attribute__((ext_vector_type(8))) short short8;
typedef __attribute__((ext_vector_type(4))) float f32x4;
typedef __attribute__((ext_vector_type(4))) int   i32x4;

__device__ __forceinline__ unsigned short f2bf(float f) {
    __hip_bfloat16 h = __float2bfloat16(f);
    return __builtin_bit_cast(unsigned short, h);
}

__device__ __forceinline__ void gload16(const void* g, void* l) {
    __builtin_amdgcn_global_load_lds(
        (const __attribute__((address_space(1))) unsigned int*)g,
        (__attribute__((address_space(3))) unsigned int*)l,
        16, 0, 0);
}

// ---------------- pre-pass 1: W int32 -> i8 pack (exact, |v|<=127) ----------------
__global__ void wpack_kernel(const int* __restrict__ W, int* __restrict__ Wq, int n16) {
    int idx = blockIdx.x * blockDim.x + threadIdx.x;
    int stride = gridDim.x * blockDim.x;
    for (int i = idx; i < n16; i += stride) {
        const int4* p = (const int4*)W + (size_t)i * 4;
        i32x4 o;
#pragma unroll
        for (int j = 0; j < 4; ++j) {
            int4 v = p[j];
            o[j] = (v.x & 0xff) | ((v.y & 0xff) << 8) | ((v.z & 0xff) << 16) | (v.w << 24);
        }
        *(i32x4*)(Wq + (size_t)i * 4) = o;
    }
}

// ---------------- pre-pass 2: X f32 -> per-row i8 quant ----------------
__global__ __launch_bounds__(256)
void xquant_kernel(const float* __restrict__ X, int* __restrict__ Xq,
                   float* __restrict__ sx) {
    const int r = blockIdx.x;            // row 0..1023
    const int t = threadIdx.x;           // 0..255, 16 elems each
    const float* xr = X + (size_t)r * K_TOT + t * 16;
    f32x4 v[4];
    float amax = 0.0f;
#pragma unroll
    for (int j = 0; j < 4; ++j) {
        v[j] = *(const f32x4*)(xr + j * 4);
#pragma unroll
        for (int e = 0; e < 4; ++e) amax = fmaxf(amax, fabsf(v[j][e]));
    }
#pragma unroll
    for (int k = 1; k < 64; k <<= 1) amax = fmaxf(amax, __shfl_xor(amax, k));
    __shared__ float sm[4];
    if ((t & 63) == 0) sm[t >> 6] = amax;
    __syncthreads();
    amax = fmaxf(fmaxf(sm[0], sm[1]), fmaxf(sm[2], sm[3]));
    const float inv = (amax > 0.0f) ? (127.0f / amax) : 0.0f;
    if (t == 0) sx[r] = (amax > 0.0f) ? (amax / 127.0f) : 0.0f;
    i32x4 o;
#pragma unroll
    for (int j = 0; j < 4; ++j) {
        int q[4];
#pragma unroll
        for (int e = 0; e < 4; ++e) {
            int qi = (int)rintf(v[j][e] * inv);
            qi = qi > 127 ? 127 : (qi < -127 ? -127 : qi);
            q[e] = qi;
        }
        o[j] = (q[0] & 0xff) | ((q[1] & 0xff) << 8) | ((q[2] & 0xff) << 16) | (q[3] << 24);
    }
    *(i32x4*)(Xq + (size_t)r * (K_TOT / 4) + t * 4) = o;
}

// ---------------- main GEMM: i8 NT, 256^2, R7 schedule ----------------
__global__ __launch_bounds__(512, 2)
void gemm_i8_kernel(const char* __restrict__ Xq,    // [1024,4096] i8
                    const char* __restrict__ Wq,    // [11008,4096] i8
                    const float* __restrict__ sx,   // [1024] row scales
                    const float* __restrict__ scale,
                    const float* __restrict__ bias,
                    float* __restrict__ out) {      // [1024,11008]
    __shared__ __align__(16) unsigned char lds[2 * BUFB];   // 128 KB

    const int tid  = threadIdx.x;
    const int lane = tid & 63;
    const int wid  = tid >> 6;        // 0..7
    const int wr   = wid >> 2;        // 0..1  (128-row half)
    const int wc   = wid & 3;         // 0..3  (64-col strip)
    const int lr   = lane & 15;
    const int kb   = lane >> 4;       // 0..3

    const int brow = blockIdx.y * BM;
    const int bcol = blockIdx.x * BN;

    // staging: per wave 32 rows A + 32 rows B (128 B each) = 4+4 gloads.
    // gload_lds dest linear; global source 16B-slot pre-swizzled:
    // src slot = (l&7) ^ (l>>3)  (row-in-chunk = l>>3).
    const int s_row  = wid * 32 + (lane >> 3);
    const int s_colb = (((lane & 7) ^ (lane >> 3)) * 16);   // bytes

    const char* asrc0 = Xq + (size_t)(brow + s_row) * K_TOT + s_colb;
    const char* bsrc0 = Wq + (size_t)(bcol + s_row) * K_TOT + s_colb;
    const int lds_row0 = wid * 32;

    auto stageA = [&](int t, unsigned char* buf) {
        const size_t k0 = (size_t)t * BKI;
#pragma unroll
        for (int i = 0; i < 4; ++i)
            gload16(asrc0 + k0 + (size_t)i * 8 * K_TOT, buf + (lds_row0 + i * 8) * BKI);
    };
    auto stageB = [&](int t, unsigned char* buf) {
        const size_t k0 = (size_t)t * BKI;
#pragma unroll
        for (int i = 0; i < 4; ++i)
            gload16(bsrc0 + k0 + (size_t)i * 8 * K_TOT, buf + ABYTES + (lds_row0 + i * 8) * BKI);
    };

    i32x4 acc[8][4];
#pragma unroll
    for (int m = 0; m < 8; ++m)
#pragma unroll
        for (int n = 0; n < 4; ++n)
#pragma unroll
            for (int i = 0; i < 4; ++i) acc[m][n][i] = 0;

    // one K-tile (K=128): reads cur, stages tile tn -> nxt
    auto do_tile = [&](const unsigned char* cur, unsigned char* nxt, int tn) {
        stageA(tn, nxt);
        asm volatile("s_waitcnt vmcnt(4)" ::: "memory");   // tile-t A,B landed (this wave)
        __builtin_amdgcn_s_barrier();                      // all waves' => cur visible
        __builtin_amdgcn_sched_barrier(0);

        i32x4 a0[4], a1[4], a2[4], a3[4], b0[4], b1[4];
        const int c0 = (kb * 16);          // kk=0 byte col (slot kb)
        const int c1 = (64 + kb * 16);     // kk=1 byte col (slot 4+kb)

        // G0: B(kk0) + A(kk0, m-half0)
#pragma unroll
        for (int n = 0; n < 4; ++n) {
            int row = wc * 64 + n * 16 + lr;
            b0[n] = *(const i32x4*)(cur + ABYTES + row * BKI + (c0 ^ ((row & 7) << 4)));
        }
#pragma unroll
        for (int m = 0; m < 4; ++m) {
            int row = wr * 128 + m * 16 + lr;
            a0[m] = *(const i32x4*)(cur + row * BKI + (c0 ^ ((row & 7) << 4)));
        }
        // G1: A(kk0, m-half1)
#pragma unroll
        for (int m = 0; m < 4; ++m) {
            int row = wr * 128 + 64 + m * 16 + lr;
            a1[m] = *(const i32x4*)(cur + row * BKI + (c0 ^ ((row & 7) << 4)));
        }

        // P0
        __builtin_amdgcn_s_setprio(1);
#pragma unroll
        for (int m = 0; m < 4; ++m)
#pragma unroll
            for (int n = 0; n < 4; ++n)
                acc[m][n] = __builtin_amdgcn_mfma_i32_16x16x64_i8(a0[m], b0[n], acc[m][n], 0, 0, 0);
        __builtin_amdgcn_s_setprio(0);

        // G2: B(kk1) + A(kk1, m-half0)
#pragma unroll
        for (int n = 0; n < 4; ++n) {
            int row = wc * 64 + n * 16 + lr;
            b1[n] = *(const i32x4*)(cur + ABYTES + row * BKI + (c1 ^ ((row & 7) << 4)));
        }
#pragma unroll
        for (int m = 0; m < 4; ++m) {
            int row = wr * 128 + m * 16 + lr;
            a2[m] = *(const i32x4*)(cur + row * BKI + (c1 ^ ((row & 7) << 4)));
        }

        // P1
        __builtin_amdgcn_s_setprio(1);
#pragma unroll
        for (int m = 0; m < 4; ++m)
#pragma unroll
            for (int n = 0; n < 4; ++n)
                acc[4 + m][n] = __builtin_amdgcn_mfma_i32_16x16x64_i8(a1[m], b0[n], acc[4 + m][n], 0, 0, 0);
        __builtin_amdgcn_s_setprio(0);

        // G3: A(kk1, m-half1); stage B of next tile mid-compute
#pragma unroll
        for (int m = 0; m < 4; ++m) {
            int row = wr * 128 + 64 + m * 16 + lr;
            a3[m] = *(const i32x4*)(cur + row * BKI + (c1 ^ ((row & 7) << 4)));
        }
        stageB(tn, nxt);

        // P2
        __builtin_amdgcn_s_setprio(1);
#pragma unroll
        for (int m = 0; m < 4; ++m)
#pragma unroll
            for (int n = 0; n < 4; ++n)
                acc[m][n] = __builtin_amdgcn_mfma_i32_16x16x64_i8(a2[m], b1[n], acc[m][n], 0, 0, 0);
        __builtin_amdgcn_s_setprio(0);

        // P3
        __builtin_amdgcn_s_setprio(1);
#pragma unroll
        for (int m = 0; m < 4; ++m)
#pragma unroll
            for (int n = 0; n < 4; ++n)
                acc[4 + m][n] = __builtin_amdgcn_mfma_i32_16x16x64_i8(a3[m], b1[n], acc[4 + m][n], 0, 0, 0);
        __builtin_amdgcn_s_setprio(0);

        asm volatile("s_waitcnt lgkmcnt(0)" ::: "memory");
        __builtin_amdgcn_s_barrier();                      // WAR: cur re-staged next tile
    };

    unsigned char* buf0 = lds;
    unsigned char* buf1 = lds + BUFB;

    stageA(0, buf0);
    stageB(0, buf0);

    for (int t = 0; t < NTI; t += 2) {
        do_tile(buf0, buf1, t + 1);
        do_tile(buf1, buf0, (t + 2 < NTI) ? t + 2 : 0);
    }

    // epilogue: out = acc * (sx[row]*scale) + bias
    const float sw = scale[0];
    const int orow0 = brow + wr * 128;
    const int ocol0 = bcol + wc * 64;
    float bv[4];
#pragma unroll
    for (int n = 0; n < 4; ++n) bv[n] = bias[ocol0 + n * 16 + lr];
#pragma unroll
    for (int m = 0; m < 8; ++m) {
        // C/D: row=(lane>>4)*4+reg, col=lane&15; rows kb*4..kb*4+3 are 4-aligned
        f32x4 sx4 = *(const f32x4*)(sx + orow0 + m * 16 + kb * 4);
#pragma unroll
        for (int i = 0; i < 4; ++i) {
            int r = orow0 + m * 16 + kb * 4 + i;
            size_t base = (size_t)r * N_TOT + ocol0;
            float fs = sx4[i] * sw;
#pragma unroll
            for (int n = 0; n < 4; ++n)
                out[base + n * 16 + lr] = (float)acc[m][n][i] * fs + bv[n];
        }
    }
}

// ---------------- fallback (round-1 fused bf16 kernel) if ws too small ----------------
__device__ __forceinline__ unsigned long long pack4(float a, float b, float c, float d) {
    return (unsigned long long)f2bf(a)
         | ((unsigned long long)f2bf(b) << 16)
         | ((unsigned long long)f2bf(c) << 32)
         | ((unsigned long long)f2bf(d) << 48);
}

#define FBM 128
#define FBN 128
#define FBK 64
#define FNT (K_TOT / FBK)

__global__ __launch_bounds__(256, 2)
void otf_linear_fused(const float* __restrict__ X, const int* __restrict__ W,
                      const float* __restrict__ scale, const float* __restrict__ bias,
                      float* __restrict__ out) {
    __shared__ __align__(16) unsigned char AsB[FBM * FBK * 2];
    __shared__ __align__(16) unsigned char BsB[FBN * FBK * 2];

    const int tid = threadIdx.x, lane = tid & 63, wid = tid >> 6;
    const int wr = wid >> 1, wc = wid & 1, lr = lane & 15, kb = lane >> 4;
    const int brow = blockIdx.y * FBM, bcol = blockIdx.x * FBN;
    const int srow = tid >> 4, sc4 = tid & 15;

    f32x4 areg[8];
    int4 breg[8];
    auto load_tiles = [&](int t) {
        const int k0 = t * FBK;
#pragma unroll
        for (int p = 0; p < 8; ++p) {
            int row = p * 16 + srow;
            areg[p] = *(const f32x4*)(&X[(size_t)(brow + row) * K_TOT + k0 + sc4 * 4]);
            breg[p] = *(const int4*)(&W[(size_t)(bcol + row) * K_TOT + k0 + sc4 * 4]);
        }
    };
    auto store_tiles = [&]() {
#pragma unroll
        for (int p = 0; p < 8; ++p) {
            int row = p * 16 + srow;
            int boff = (sc4 * 8) ^ ((row & 7) << 4);
            *(unsigned long long*)(&AsB[row * 128 + boff]) =
                pack4(areg[p][0], areg[p][1], areg[p][2], areg[p][3]);
            *(unsigned long long*)(&BsB[row * 128 + boff]) =
                pack4((float)breg[p].x, (float)breg[p].y, (float)breg[p].z, (float)breg[p].w);
        }
    };

    f32x4 acc[4][4];
#pragma unroll
    for (int m = 0; m < 4; ++m)
#pragma unroll
        for (int n = 0; n < 4; ++n)
#pragma unroll
            for (int i = 0; i < 4; ++i) acc[m][n][i] = 0.0f;

    load_tiles(0);
    for (int t = 0; t < FNT; ++t) {
        store_tiles();
        __syncthreads();
        if (t + 1 < FNT) load_tiles(t + 1);
#pragma unroll
        for (int kk = 0; kk < 2; ++kk) {
            short8 af[4], bfr[4];
#pragma unroll
            for (int m = 0; m < 4; ++m) {
                int row = wr * 64 + m * 16 + lr;
                int col = (kk * 64 + kb * 16) ^ ((row & 7) << 4);
                af[m] = *(const short8*)(&AsB[row * 128 + col]);
            }
#pragma unroll
            for (int n = 0; n < 4; ++n) {
                int row = wc * 64 + n * 16 + lr;
                int col = (kk * 64 + kb * 16) ^ ((row & 7) << 4);
                bfr[n] = *(const short8*)(&BsB[row * 128 + col]);
            }
#pragma unroll
            for (int m = 0; m < 4; ++m)
#pragma unroll
                for (int n = 0; n < 4; ++n)
                    acc[m][n] = __builtin_amdgcn_mfma_f32_16x16x32_bf16(af[m], bfr[n], acc[m][n], 0, 0, 0);
        }
        __syncthreads();
    }

    const float sc = scale[0];
    const int orow0 = brow + wr * 64, ocol0 = bcol + wc * 64;
    float bv[4];
#pragma unroll
    for (int n = 0; n < 4; ++n) bv[n] = bias[ocol0 + n * 16 + lr];
#pragma unroll
    for (int m = 0; m < 4; ++m)
#pragma unroll
        for (int i = 0; i < 4; ++i) {
            int r = orow0 + m * 16 + kb * 4 + i;
            size_t base = (size_t)r * N_TOT + ocol0;
#pragma unroll
            for (int n = 0; n < 4; ++n)
                out[base + n * 16 + lr] = acc[m][n][i] * sc + bv[n];
        }
}

extern "C" void kernel_launch(void* const* d_in, const int* in_sizes, int n_in,
                              void* d_out, int out_size, void* d_ws, size_t ws_size,
                              hipStream_t stream) {
    const float* x     = (const float*)d_in[0];
    const int*   w     = (const int*)d_in[1];
    const float* scale = (const float*)d_in[2];
    const float* bias  = (const float*)d_in[3];
    float* out = (float*)d_out;

    const size_t W_ELEMS = (size_t)N_TOT * K_TOT;   // 45,088,768
    const size_t X_ELEMS = (size_t)M_TOT * K_TOT;   //  4,194,304
    const size_t need = W_ELEMS + X_ELEMS + M_TOT * sizeof(float);  // ~49.3 MB

    if (ws_size >= need) {
        char*  Wq = (char*)d_ws;
        char*  Xq = (char*)d_ws + W_ELEMS;
        float* sx = (float*)((char*)d_ws + W_ELEMS + X_ELEMS);
        wpack_kernel<<<2048, 256, 0, stream>>>(w, (int*)Wq, (int)(W_ELEMS / 16));
        xquant_kernel<<<M_TOT, 256, 0, stream>>>(x, (int*)Xq, sx);
        gemm_i8_kernel<<<dim3(N_TOT / BN, M_TOT / BM), 512, 0, stream>>>(
            Xq, Wq, sx, scale, bias, out);
    } else {
        otf_linear_fused<<<dim3(N_TOT / FBN, M_TOT / FBM), 256, 0, stream>>>(x, w, scale, bias, out);
    }
}